// Round 1
// baseline (5327.003 us; speedup 1.0000x reference)
//
#include <hip/hip_runtime.h>
#include <cstdint>
#include <cstddef>

#define Bq 256        // queries
#define Cdim 1024     // feature dim
#define Mpts 200000   // bank points
#define Ktop 16       // k
#define SUB 64        // points per register sub-tile
#define KC 32         // C-chunk staged per iteration
#define NSUB (Mpts / SUB)   // 3125 (exact: 200000 = 3125*64)
#define GB 512        // grid blocks for gemm kernel
#define QS_LD (Bq + 4)
#define PS_LD (SUB + 4)

static_assert(Mpts % SUB == 0, "M must be a multiple of SUB");

// ---------------------------------------------------------------------------
// Kernel 1: fused fp32 GEMM (scores r = ||p||^2 - 2 q.p) + streaming top-16
// per query per block. Each block owns a contiguous slice of M.
// Thread layout for compute: tid -> (qg = tid>>2 in 0..63, pg = tid&3):
//   thread owns queries qg*4..qg*4+3 and points pg*16..pg*16+15  (64 fp32 acc)
// Wave w owns queries 64w..64w+63 entirely -> top-k LDS rows are
// wave-private; insertion serialized over pg via wave-internal turns.
// ---------------------------------------------------------------------------
__global__ __launch_bounds__(256, 2) void knn_gemm_topk(
    const float* __restrict__ query, const float* __restrict__ bank,
    float* __restrict__ candd, int* __restrict__ candi) {
  __shared__ float Qs[KC][QS_LD];   // transposed: Qs[dim][query]
  __shared__ float Ps[KC][PS_LD];   // transposed: Ps[dim][point]
  __shared__ float topd[Bq][Ktop];  // running top-16 distances (sorted asc)
  __shared__ int   topi[Bq][Ktop];  // matching indices
  __shared__ float pnbuf[SUB];      // ||p||^2 for current sub-tile

  const int tid  = threadIdx.x;
  const int qg   = tid >> 2;   // 0..63
  const int pg   = tid & 3;    // 0..3
  const int co   = tid & 7;    // staging: float4 column group (8 x 4 = 32 dims)
  const int row0 = tid >> 3;   // staging: row 0..31 (+32 per pass)

  // init top-k
  #pragma unroll
  for (int j = 0; j < Ktop; ++j) { topd[tid][j] = INFINITY; topi[tid][j] = 0; }
  __syncthreads();

  const int t0 = (int)((long long)blockIdx.x * NSUB / GB);
  const int t1 = (int)(((long long)blockIdx.x + 1) * NSUB / GB);

  for (int t = t0; t < t1; ++t) {
    const int m0 = t * SUB;
    float acc[4][16];
    #pragma unroll
    for (int i = 0; i < 4; ++i)
      #pragma unroll
      for (int j = 0; j < 16; ++j) acc[i][j] = 0.f;
    float pnacc = 0.f;  // meaningful on tid < 64 only

    for (int c0 = 0; c0 < Cdim; c0 += KC) {
      // ---- stage Q chunk [256 q x 32 dims], transposed into Qs ----
      // global: lanes 0..7 read one full 128B line of a query row (coalesced)
      #pragma unroll
      for (int pass = 0; pass < 8; ++pass) {
        const int q = row0 + pass * 32;
        const float4 v = *(const float4*)&query[(size_t)q * Cdim + c0 + co * 4];
        Qs[co * 4 + 0][q] = v.x; Qs[co * 4 + 1][q] = v.y;
        Qs[co * 4 + 2][q] = v.z; Qs[co * 4 + 3][q] = v.w;
      }
      // ---- stage P chunk [64 pts x 32 dims], transposed into Ps ----
      #pragma unroll
      for (int pass = 0; pass < 2; ++pass) {
        const int pt = row0 + pass * 32;
        const float4 v = *(const float4*)&bank[(size_t)(m0 + pt) * Cdim + c0 + co * 4];
        Ps[co * 4 + 0][pt] = v.x; Ps[co * 4 + 1][pt] = v.y;
        Ps[co * 4 + 2][pt] = v.z; Ps[co * 4 + 3][pt] = v.w;
      }
      __syncthreads();

      // fused ||p||^2 partial (wave 0 only; 2-way LDS aliasing = free)
      if (tid < SUB) {
        #pragma unroll
        for (int d = 0; d < KC; ++d) { const float v = Ps[d][tid]; pnacc = fmaf(v, v, pnacc); }
      }

      // ---- register-tile GEMM: 32 k-steps x (4q x 16p) ----
      #pragma unroll
      for (int kk = 0; kk < KC; ++kk) {
        const float4 q4 = *(const float4*)&Qs[kk][qg * 4];
        const float4 p0 = *(const float4*)&Ps[kk][pg * 16 + 0];
        const float4 p1 = *(const float4*)&Ps[kk][pg * 16 + 4];
        const float4 p2 = *(const float4*)&Ps[kk][pg * 16 + 8];
        const float4 p3 = *(const float4*)&Ps[kk][pg * 16 + 12];
        const float qa[4]  = {q4.x, q4.y, q4.z, q4.w};
        const float pa[16] = {p0.x, p0.y, p0.z, p0.w, p1.x, p1.y, p1.z, p1.w,
                              p2.x, p2.y, p2.z, p2.w, p3.x, p3.y, p3.z, p3.w};
        #pragma unroll
        for (int i = 0; i < 4; ++i)
          #pragma unroll
          for (int j = 0; j < 16; ++j)
            acc[i][j] = fmaf(qa[i], pa[j], acc[i][j]);
      }
      __syncthreads();
    }

    // broadcast ||p||^2 of this sub-tile
    if (tid < SUB) pnbuf[tid] = pnacc;
    __syncthreads();

    float pn[16];
    #pragma unroll
    for (int j = 0; j < 16; ++j) pn[j] = pnbuf[pg * 16 + j];

    // ---- streaming top-16 insert; serialize the 4 pg-lanes per query via
    //      wave-internal turns (same-wave LDS ops complete in order) ----
    for (int turn = 0; turn < 4; ++turn) {
      if (pg == turn) {
        for (int i = 0; i < 4; ++i) {
          const int q = qg * 4 + i;
          for (int j = 0; j < 16; ++j) {
            const float r = pn[j] - 2.0f * acc[i][j];
            if (r < topd[q][Ktop - 1]) {           // strict: stable on ties
              const int idx = m0 + pg * 16 + j;
              int pos = Ktop - 1;
              while (pos > 0 && topd[q][pos - 1] > r) {
                topd[q][pos] = topd[q][pos - 1];
                topi[q][pos] = topi[q][pos - 1];
                --pos;
              }
              topd[q][pos] = r;
              topi[q][pos] = idx;
            }
          }
        }
      }
    }
    __syncthreads();
  }

  // writeout: thread tid owns query tid (same wave as its writers)
  const size_t base = (size_t)blockIdx.x * Bq * Ktop + (size_t)tid * Ktop;
  #pragma unroll
  for (int j = 0; j < Ktop; ++j) {
    candd[base + j] = topd[tid][j];
    candi[base + j] = topi[tid][j];
  }
}

// ---------------------------------------------------------------------------
// Kernel 2: per-query merge of 512 x 16 candidates -> global top-16 in
// ascending-distance order (tie-break lower index, matching lax.top_k), then
// gather the winning trajectories (24 floats each).
// ---------------------------------------------------------------------------
__global__ __launch_bounds__(256) void knn_merge(
    const float* __restrict__ candd, const int* __restrict__ candi,
    const float* __restrict__ traj, float* __restrict__ out) {
  __shared__ float ld[GB * Ktop];   // 8192
  __shared__ int   li[GB * Ktop];
  __shared__ float swd[4];
  __shared__ int   swi[4], swp[4];
  __shared__ int   bi_s;

  const int b = blockIdx.x;
  const int tid = threadIdx.x;

  for (int e = tid; e < GB * Ktop; e += 256) {
    const int blk = e >> 4, j = e & 15;
    ld[e] = candd[(size_t)blk * Bq * Ktop + (size_t)b * Ktop + j];
    li[e] = candi[(size_t)blk * Bq * Ktop + (size_t)b * Ktop + j];
  }
  __syncthreads();

  for (int r = 0; r < Ktop; ++r) {
    float d = INFINITY;
    int idx = 0x7fffffff, pos = -1;
    for (int e = tid; e < GB * Ktop; e += 256) {
      const float dv = ld[e];
      const int   iv = li[e];
      if (dv < d || (dv == d && iv < idx)) { d = dv; idx = iv; pos = e; }
    }
    // wave (64-lane) lexicographic argmin reduce
    #pragma unroll
    for (int off = 32; off > 0; off >>= 1) {
      const float od = __shfl_down(d, off, 64);
      const int   oi = __shfl_down(idx, off, 64);
      const int   op = __shfl_down(pos, off, 64);
      if (od < d || (od == d && oi < idx)) { d = od; idx = oi; pos = op; }
    }
    if ((tid & 63) == 0) { const int w = tid >> 6; swd[w] = d; swi[w] = idx; swp[w] = pos; }
    __syncthreads();
    if (tid == 0) {
      float bd = swd[0]; int bi = swi[0], bp = swp[0];
      #pragma unroll
      for (int w = 1; w < 4; ++w)
        if (swd[w] < bd || (swd[w] == bd && swi[w] < bi)) { bd = swd[w]; bi = swi[w]; bp = swp[w]; }
      bi_s = bi;
      ld[bp] = INFINITY;      // remove winner for next round
      li[bp] = 0x7fffffff;
    }
    __syncthreads();
    if (tid < 24) {
      out[(size_t)b * (Ktop * 24) + r * 24 + tid] = traj[(size_t)bi_s * 24 + tid];
    }
    __syncthreads();
  }
}

// ---------------------------------------------------------------------------
extern "C" void kernel_launch(void* const* d_in, const int* in_sizes, int n_in,
                              void* d_out, int out_size, void* d_ws, size_t ws_size,
                              hipStream_t stream) {
  const float* query = (const float*)d_in[0];   // [256, 1024]
  const float* bank  = (const float*)d_in[1];   // [200000, 1024]
  const float* traj  = (const float*)d_in[2];   // [200000, 8, 3]
  // d_in[3] is k == 16, compile-time constant here.
  float* out = (float*)d_out;                   // [256, 16, 8, 3]

  float* candd = (float*)d_ws;                                       // 8 MB
  int*   candi = (int*)((char*)d_ws + (size_t)GB * Bq * Ktop * 4);   // 8 MB

  knn_gemm_topk<<<GB, 256, 0, stream>>>(query, bank, candd, candi);
  knn_merge<<<Bq, 256, 0, stream>>>(candd, candi, traj, out);
}

// Round 2
// 1996.685 us; speedup vs baseline: 2.6679x; 2.6679x over previous
//
#include <hip/hip_runtime.h>
#include <cstdint>
#include <cstddef>

#define Bq 256        // queries
#define Cdim 1024     // feature dim
#define Mpts 200000   // bank points
#define Ktop 16       // k
#define SUB 64        // points per block sub-tile
#define KC 32         // K-chunk dims per stage
#define NCHUNK (Cdim / KC)   // 32
#define NSUB (Mpts / SUB)    // 3125
#define GB 512        // gemm grid blocks (2 per CU)

static_assert(Mpts % SUB == 0, "M must divide");

typedef __bf16 bf16x8 __attribute__((ext_vector_type(8)));
typedef __bf16 bf16x4 __attribute__((ext_vector_type(4)));
typedef float  f32x4  __attribute__((ext_vector_type(4)));

#define GLDS16(g, l)                                                          \
  __builtin_amdgcn_global_load_lds(                                           \
      (const __attribute__((address_space(1))) void*)(g),                     \
      (__attribute__((address_space(3))) void*)(l), 16, 0, 0)

// ---------------------------------------------------------------------------
// Kernel 0: pack query [256x1024] fp32 into MFMA B-fragment image, split
// bf16 hi/lo. Layout: qp[c][term][ntile][quad][lane16][j8] (__bf16),
// c = k>>5, quad = (k>>3)&3, j = k&7, ntile = q>>4, lane = q&15.
// Total 32 chunks x 32 KB = 1 MB.
// ---------------------------------------------------------------------------
__global__ void pack_q(const float* __restrict__ q, __bf16* __restrict__ qp) {
  const int qi = blockIdx.x;          // query 0..255
  const int k0 = threadIdx.x * 4;     // dim 0..1023, step 4
  const float4 v = *(const float4*)&q[(size_t)qi * Cdim + k0];
  const float f[4] = {v.x, v.y, v.z, v.w};
  bf16x4 hv, lv;
#pragma unroll
  for (int e = 0; e < 4; ++e) {
    const __bf16 h = (__bf16)f[e];
    hv[e] = h;
    lv[e] = (__bf16)(f[e] - (float)h);
  }
  const int c    = k0 >> 5;
  const int quad = (k0 >> 3) & 3;
  const int j0   = k0 & 7;            // 0 or 4
  const size_t base = (size_t)c * 16384 +
                      ((size_t)(qi >> 4) * 4 + quad) * 128 + (qi & 15) * 8 + j0;
  *(bf16x4*)&qp[base]        = hv;    // term 0 = hi
  *(bf16x4*)&qp[base + 8192] = lv;    // term 1 = lo
}

// ---------------------------------------------------------------------------
// Kernel 1: split-bf16 MFMA GEMM (scores r = ||p||^2 - 2 q.p) + streaming
// top-16. Block: 4 waves, tile 64 pts x 256 queries. Wave w owns queries
// 64w..64w+63 (4 n-tiles) x all 4 m-tiles -> 16 MFMA tiles, f32x4 acc each.
// Per K-chunk: Q frags via global_load_lds (pre-packed), P loaded fp32,
// converted hi/lo, staged in fragment order. 48 MFMAs/wave/chunk.
// ---------------------------------------------------------------------------
__global__ __launch_bounds__(256, 2) void knn_gemm_topk(
    const float* __restrict__ bank, const __bf16* __restrict__ qp,
    float* __restrict__ candd, int* __restrict__ candi) {
  // [term][ntile][quad][lane16][j8]
  __shared__ __attribute__((aligned(16))) __bf16 Qs[2][16][4][16][8];  // 32 KB
  __shared__ __attribute__((aligned(16))) __bf16 Ps[2][4][4][16][8];   //  8 KB
  __shared__ float topd[Bq][17];   // padded: conflict-free threshold reads
  __shared__ int   topi[Bq][17];
  __shared__ float pn4[SUB][4];
  __shared__ float pnb[SUB];

  const int tid  = threadIdx.x;
  const int w    = tid >> 6;      // wave 0..3
  const int lane = tid & 63;
  const int l    = lane & 15;
  const int quad = lane >> 4;
  const int sp   = tid >> 2;      // staging point 0..63
  const int skq  = tid & 3;       // staging k-quad (8 dims each)

#pragma unroll
  for (int j = 0; j < Ktop; ++j) { topd[tid][j] = INFINITY; topi[tid][j] = 0; }
  __syncthreads();

  const int t0 = (int)((long long)blockIdx.x * NSUB / GB);
  const int t1 = (int)(((long long)blockIdx.x + 1) * NSUB / GB);

#pragma unroll 1
  for (int t = t0; t < t1; ++t) {
    const int m0 = t * SUB;
    f32x4 acc[4][4];
#pragma unroll
    for (int mt = 0; mt < 4; ++mt)
#pragma unroll
      for (int nt = 0; nt < 4; ++nt) {
        const f32x4 z = {0.f, 0.f, 0.f, 0.f};
        acc[mt][nt] = z;
      }
    float nrm = 0.f;
    const float* prow = bank + (size_t)(m0 + sp) * Cdim + skq * 8;

#pragma unroll 1
    for (int c = 0; c < NCHUNK; ++c) {
      // ---- async Q-fragment DMA: 8 KB per wave (32 KB total) ----
      {
        const char* g  = (const char*)qp + (size_t)c * 32768 + w * 8192 + lane * 16;
        char*       lb = (char*)&Qs[0][0][0][0][0] + w * 8192;
#pragma unroll
        for (int i = 0; i < 8; ++i) GLDS16(g + i * 1024, lb + i * 1024);
      }
      // ---- P chunk: 8 fp32 per thread, fused norm, split-bf16, stage ----
      {
        const float4 va = *(const float4*)(prow + c * KC);
        const float4 vb = *(const float4*)(prow + c * KC + 4);
        const float f[8] = {va.x, va.y, va.z, va.w, vb.x, vb.y, vb.z, vb.w};
        bf16x8 hv, lv;
#pragma unroll
        for (int e = 0; e < 8; ++e) {
          nrm = fmaf(f[e], f[e], nrm);
          const __bf16 h = (__bf16)f[e];
          hv[e] = h;
          lv[e] = (__bf16)(f[e] - (float)h);
        }
        *(bf16x8*)&Ps[0][sp >> 4][skq][sp & 15][0] = hv;
        *(bf16x8*)&Ps[1][sp >> 4][skq][sp & 15][0] = lv;
      }
      __syncthreads();

      // ---- MFMA: 4 m-tiles x 4 n-tiles x 3 split terms ----
      bf16x8 Ah[4], Al[4];
#pragma unroll
      for (int mt = 0; mt < 4; ++mt) {
        Ah[mt] = *(bf16x8*)&Ps[0][mt][quad][l][0];
        Al[mt] = *(bf16x8*)&Ps[1][mt][quad][l][0];
      }
#pragma unroll
      for (int nt = 0; nt < 4; ++nt) {
        const bf16x8 Bh = *(bf16x8*)&Qs[0][w * 4 + nt][quad][l][0];
        const bf16x8 Bl = *(bf16x8*)&Qs[1][w * 4 + nt][quad][l][0];
#pragma unroll
        for (int mt = 0; mt < 4; ++mt) {
          acc[mt][nt] = __builtin_amdgcn_mfma_f32_16x16x32_bf16(Ah[mt], Bh, acc[mt][nt], 0, 0, 0);
          acc[mt][nt] = __builtin_amdgcn_mfma_f32_16x16x32_bf16(Ah[mt], Bl, acc[mt][nt], 0, 0, 0);
          acc[mt][nt] = __builtin_amdgcn_mfma_f32_16x16x32_bf16(Al[mt], Bh, acc[mt][nt], 0, 0, 0);
        }
      }
      __syncthreads();
    }

    // ---- point norms (fp32, exact-path) ----
    pn4[sp][skq] = nrm;
    __syncthreads();
    if (tid < SUB) pnb[tid] = (pn4[tid][0] + pn4[tid][1]) + (pn4[tid][2] + pn4[tid][3]);
    __syncthreads();

    // ---- epilogue: streaming top-16, wave-private queries ----
    // D layout: row(point-in-tile) = quad*4 + r, col(query-in-tile) = lane&15
#pragma unroll
    for (int nt = 0; nt < 4; ++nt) {
      const int q = (w * 4 + nt) * 16 + l;
      const float thr = topd[q][15];
      float dist[4][4];
      float mn = INFINITY;
#pragma unroll
      for (int mt = 0; mt < 4; ++mt)
#pragma unroll
        for (int r = 0; r < 4; ++r) {
          const float dv = fmaf(-2.0f, acc[mt][nt][r], pnb[mt * 16 + quad * 4 + r]);
          dist[mt][r] = dv;
          mn = fminf(mn, dv);
        }
      if (__ballot(mn < thr) != 0ULL) {
        // rare path: serialize the 4 quads (same-wave LDS ops are in-order);
        // lanes within a turn own distinct q.
#pragma unroll 1
        for (int turn = 0; turn < 4; ++turn) {
          if (quad == turn && mn < topd[q][15]) {
#pragma unroll
            for (int mt = 0; mt < 4; ++mt)
#pragma unroll
              for (int r = 0; r < 4; ++r) {
                const float dv = dist[mt][r];
                if (dv < topd[q][15]) {   // live re-check (strict: stable ties)
                  const int idx = m0 + mt * 16 + quad * 4 + r;
                  int pos = 15;
                  while (pos > 0 && topd[q][pos - 1] > dv) {
                    topd[q][pos] = topd[q][pos - 1];
                    topi[q][pos] = topi[q][pos - 1];
                    --pos;
                  }
                  topd[q][pos] = dv;
                  topi[q][pos] = idx;
                }
              }
          }
        }
      }
    }
  }

  __syncthreads();
  const size_t base = (size_t)blockIdx.x * Bq * Ktop + (size_t)tid * Ktop;
#pragma unroll
  for (int j = 0; j < Ktop; ++j) {
    candd[base + j] = topd[tid][j];
    candi[base + j] = topi[tid][j];
  }
}

// ---------------------------------------------------------------------------
// Kernel 2: per-query merge of 512 x 16 candidates -> global top-16 ordered
// (tie-break lower index, matching lax.top_k), gather trajectories.
// ---------------------------------------------------------------------------
__global__ __launch_bounds__(256) void knn_merge(
    const float* __restrict__ candd, const int* __restrict__ candi,
    const float* __restrict__ traj, float* __restrict__ out) {
  __shared__ float ld[GB * Ktop];
  __shared__ int   li[GB * Ktop];
  __shared__ float swd[4];
  __shared__ int   swi[4], swp[4];
  __shared__ int   bi_s;

  const int b = blockIdx.x;
  const int tid = threadIdx.x;

  for (int e = tid; e < GB * Ktop; e += 256) {
    const int blk = e >> 4, j = e & 15;
    ld[e] = candd[(size_t)blk * Bq * Ktop + (size_t)b * Ktop + j];
    li[e] = candi[(size_t)blk * Bq * Ktop + (size_t)b * Ktop + j];
  }
  __syncthreads();

  for (int r = 0; r < Ktop; ++r) {
    float d = INFINITY;
    int idx = 0x7fffffff, pos = -1;
    for (int e = tid; e < GB * Ktop; e += 256) {
      const float dv = ld[e];
      const int   iv = li[e];
      if (dv < d || (dv == d && iv < idx)) { d = dv; idx = iv; pos = e; }
    }
#pragma unroll
    for (int off = 32; off > 0; off >>= 1) {
      const float od = __shfl_down(d, off, 64);
      const int   oi = __shfl_down(idx, off, 64);
      const int   op = __shfl_down(pos, off, 64);
      if (od < d || (od == d && oi < idx)) { d = od; idx = oi; pos = op; }
    }
    if ((tid & 63) == 0) { const int wv = tid >> 6; swd[wv] = d; swi[wv] = idx; swp[wv] = pos; }
    __syncthreads();
    if (tid == 0) {
      float bd = swd[0]; int bi = swi[0], bp = swp[0];
#pragma unroll
      for (int wv = 1; wv < 4; ++wv)
        if (swd[wv] < bd || (swd[wv] == bd && swi[wv] < bi)) { bd = swd[wv]; bi = swi[wv]; bp = swp[wv]; }
      bi_s = bi;
      ld[bp] = INFINITY;
      li[bp] = 0x7fffffff;
    }
    __syncthreads();
    if (tid < 24) {
      out[(size_t)b * (Ktop * 24) + r * 24 + tid] = traj[(size_t)bi_s * 24 + tid];
    }
    __syncthreads();
  }
}

// ---------------------------------------------------------------------------
extern "C" void kernel_launch(void* const* d_in, const int* in_sizes, int n_in,
                              void* d_out, int out_size, void* d_ws, size_t ws_size,
                              hipStream_t stream) {
  const float* query = (const float*)d_in[0];   // [256, 1024]
  const float* bank  = (const float*)d_in[1];   // [200000, 1024]
  const float* traj  = (const float*)d_in[2];   // [200000, 8, 3]
  float* out = (float*)d_out;                   // [256, 16, 8, 3]

  __bf16* qpack = (__bf16*)d_ws;                                        // 1 MB
  float*  candd = (float*)((char*)d_ws + (1 << 20));                    // 8.4 MB
  int*    candi = (int*)((char*)d_ws + (1 << 20) +
                         (size_t)GB * Bq * Ktop * 4);                   // 8.4 MB

  pack_q<<<Bq, 256, 0, stream>>>(query, qpack);
  knn_gemm_topk<<<GB, 256, 0, stream>>>(bank, qpack, candd, candi);
  knn_merge<<<Bq, 256, 0, stream>>>(candd, candi, traj, out);
}